// Round 6
// baseline (229.348 us; speedup 1.0000x reference)
//
#include <hip/hip_runtime.h>
#include <hip/hip_bf16.h>
#include <stdint.h>

typedef __attribute__((ext_vector_type(8))) short short8;
typedef __attribute__((ext_vector_type(4))) float f32x4;
typedef const __attribute__((address_space(1))) uint32_t* gas1_t;
typedef __attribute__((address_space(3))) uint32_t* las3_t;

__device__ __forceinline__ short f2bf(float f) {
  uint32_t u = __builtin_bit_cast(uint32_t, f);
  u += 0x7fffu + ((u >> 16) & 1u);
  return (short)(u >> 16);
}
__device__ __forceinline__ float bf2f(short s) {
  return __builtin_bit_cast(float, ((uint32_t)(uint16_t)s) << 16);
}

// ---- gather the 4 bias vectors into one contiguous buffer ----
__global__ __launch_bounds__(256) void bias_gather_k(const float* b0, const float* b1,
    const float* b2, const float* b3, float* __restrict__ dst) {
  int i = blockIdx.x * 256 + threadIdx.x;
  if (i >= 4096) return;
  int z = i >> 10, j = i & 1023;
  const float* s = (z==0)?b0:(z==1)?b1:(z==2)?b2:b3;
  dst[i] = s[j];
}

// ---- weights: W[K=1024,N=1024] f32 -> Wt[N,K] bf16 (z selects weight) ----
__global__ __launch_bounds__(256) void wt_cvt_k(const float* w0, const float* w1,
    const float* w2, const float* w3, short* __restrict__ dst) {
  __shared__ float t[32][33];
  const float* W = (blockIdx.z==0)?w0:(blockIdx.z==1)?w1:(blockIdx.z==2)?w2:w3;
  short* D = dst + (long long)blockIdx.z * 1048576LL;
  int n0 = blockIdx.x * 32, k0 = blockIdx.y * 32;
  int tx = threadIdx.x, ty = threadIdx.y;
  #pragma unroll
  for (int i = 0; i < 4; ++i)
    t[ty + 8*i][tx] = W[(long long)(k0 + ty + 8*i) * 1024 + n0 + tx];
  __syncthreads();
  #pragma unroll
  for (int i = 0; i < 4; ++i)
    D[(long long)(n0 + ty + 8*i) * 1024 + k0 + tx] = f2bf(t[tx][ty + 8*i]);
}

// ---- in-place row softmax on bf16 [rows,2048] ----
__global__ __launch_bounds__(256) void softmax_bf_k(short* __restrict__ SP) {
  short* sp = SP + (long long)blockIdx.x * 2048;
  const int t = threadIdx.x;
  short8 sv = *(const short8*)(sp + t*8);
  float v[8];
  #pragma unroll
  for (int j = 0; j < 8; ++j) v[j] = bf2f(sv[j]);
  float m = v[0];
  #pragma unroll
  for (int j = 1; j < 8; ++j) m = fmaxf(m, v[j]);
  #pragma unroll
  for (int off = 32; off > 0; off >>= 1) m = fmaxf(m, __shfl_down(m, off, 64));
  __shared__ float rmax[4], rsum[4];
  int wv = t >> 6, ln = t & 63;
  if (ln == 0) rmax[wv] = m;
  __syncthreads();
  m = fmaxf(fmaxf(rmax[0], rmax[1]), fmaxf(rmax[2], rmax[3]));
  float e[8], sum = 0.f;
  #pragma unroll
  for (int j = 0; j < 8; ++j) { e[j] = exp2f((v[j] - m) * 1.44269504f); sum += e[j]; }
  #pragma unroll
  for (int off = 32; off > 0; off >>= 1) sum += __shfl_down(sum, off, 64);
  if (ln == 0) rsum[wv] = sum;
  __syncthreads();
  float inv = 1.0f / (rsum[0] + rsum[1] + rsum[2] + rsum[3]);
  short8 o;
  #pragma unroll
  for (int j = 0; j < 8; ++j) o[j] = f2bf(e[j] * inv);
  *(short8*)(sp + t*8) = o;
}

#define MFMA16(d, a_, b_) d = __builtin_amdgcn_mfma_f32_16x16x32_bf16(a_, b_, d, 0, 0, 0)
#define LGKM0 do { asm volatile("s_waitcnt lgkmcnt(0)" ::: "memory"); \
                   __builtin_amdgcn_sched_barrier(0); } while (0)
// flattened 1-D grid + bijective XCD-chunked swizzle (nwg % 8 == 0 at all call sites)
#define XCD_DECODE(gxs_, gys_) \
  const int nwg = (int)gridDim.x; \
  const int wg = ((int)blockIdx.x & 7) * (nwg >> 3) + ((int)blockIdx.x >> 3); \
  const int bxi = wg & ((1 << (gxs_)) - 1); \
  const int byi = (wg >> (gxs_)) & ((1 << (gys_)) - 1); \
  const int z = wg >> ((gxs_) + (gys_));

// ============================================================================
// 256x256 8-phase GEMM (proven template + XCD swizzle). BK=64, 8 waves.
// ============================================================================
template<int OUT_BF16>
__global__ __launch_bounds__(512, 2) void gemm8_k(const short* __restrict__ A,
    const short* __restrict__ Bt, void* __restrict__ Cv,
    const float* __restrict__ bias,
    int M, int N, int K, long long sA, long long sB, long long sC,
    long long sBias, float scale, int gxs, int gys)
{
  __shared__ __align__(16) short lds[2][2][256*64];
  XCD_DECODE(gxs, gys);
  A  += (long long)z * sA;
  Bt += (long long)z * sB;
  const int bm = byi * 256;
  const int bn = bxi * 256;
  const int tid  = threadIdx.x;
  const int w    = tid >> 6, lane = tid & 63;
  const int wr   = w >> 2,   wc   = w & 3;
  const int lr   = lane & 15, lk  = lane >> 4;

  const int rsw0 = ((lk    ) ^ (lr & 7)) * 8;
  const int rsw1 = ((lk + 4) ^ (lr & 7)) * 8;
  const int srow = w * 8 + (lane >> 3);
  const int swc  = ((lane & 7) ^ ((lane >> 3) & 7)) * 8;
  const short* gA[4]; const short* gB[4];
  #pragma unroll
  for (int i = 0; i < 4; ++i) {
    gA[i] = A  + (long long)(bm + i*64 + srow) * K + swc;
    gB[i] = Bt + (long long)(bn + i*64 + srow) * K + swc;
  }

  #define STG(buf, ab, i, kt) \
    __builtin_amdgcn_global_load_lds((gas1_t)(((ab) ? gB : gA)[i] + (long long)(kt)*64), \
        (las3_t)&lds[buf][ab][(i)*4096 + w*512], 16, 0, 0)
  #define RDA(buf, mi, ks) (*(const short8*)&lds[buf][0][(wr*128 + (mi)*16 + lr)*64 + ((ks) ? rsw1 : rsw0)])
  #define RDB(buf, ni, ks) (*(const short8*)&lds[buf][1][(wc*64  + (ni)*16 + lr)*64 + ((ks) ? rsw1 : rsw0)])

  f32x4 acc[8][4] = {};
  const int nt = K >> 6;

  #pragma unroll
  for (int i = 0; i < 4; ++i) STG(0, 0, i, 0);
  #pragma unroll
  for (int i = 0; i < 4; ++i) STG(0, 1, i, 0);
  STG(1, 0, 0, 1); STG(1, 0, 2, 1);
  STG(1, 1, 0, 1); STG(1, 1, 1, 1);
  STG(1, 1, 2, 1); STG(1, 1, 3, 1);
  asm volatile("s_waitcnt vmcnt(6)" ::: "memory");
  __builtin_amdgcn_s_barrier();

  for (int g = 0; g < nt; ++g) {
    const int b = g & 1, nb = b ^ 1;
    short8 aR[4][2], bR[4][2];
    // phase 1
    #pragma unroll
    for (int mi = 0; mi < 4; ++mi) { aR[mi][0] = RDA(b, mi, 0); aR[mi][1] = RDA(b, mi, 1); }
    #pragma unroll
    for (int ni = 0; ni < 2; ++ni) { bR[ni][0] = RDB(b, ni, 0); bR[ni][1] = RDB(b, ni, 1); }
    if (g + 1 < nt) { STG(nb, 0, 1, g+1); STG(nb, 0, 3, g+1); }
    __builtin_amdgcn_s_barrier();
    LGKM0;
    __builtin_amdgcn_s_setprio(1);
    #pragma unroll
    for (int mi = 0; mi < 4; ++mi)
      #pragma unroll
      for (int ni = 0; ni < 2; ++ni) {
        MFMA16(acc[mi][ni], aR[mi][0], bR[ni][0]);
        MFMA16(acc[mi][ni], aR[mi][1], bR[ni][1]);
      }
    __builtin_amdgcn_s_setprio(0);
    __builtin_amdgcn_s_barrier();
    // phase 2
    #pragma unroll
    for (int ni = 2; ni < 4; ++ni) { bR[ni][0] = RDB(b, ni, 0); bR[ni][1] = RDB(b, ni, 1); }
    if (g + 2 < nt) { STG(b, 0, 0, g+2); STG(b, 0, 2, g+2); }
    __builtin_amdgcn_s_barrier();
    LGKM0;
    __builtin_amdgcn_s_setprio(1);
    #pragma unroll
    for (int mi = 0; mi < 4; ++mi)
      #pragma unroll
      for (int ni = 2; ni < 4; ++ni) {
        MFMA16(acc[mi][ni], aR[mi][0], bR[ni][0]);
        MFMA16(acc[mi][ni], aR[mi][1], bR[ni][1]);
      }
    __builtin_amdgcn_s_setprio(0);
    __builtin_amdgcn_s_barrier();
    // phase 3
    #pragma unroll
    for (int mi = 0; mi < 4; ++mi) { aR[mi][0] = RDA(b, mi+4, 0); aR[mi][1] = RDA(b, mi+4, 1); }
    if (g + 2 < nt) { STG(b, 1, 0, g+2); STG(b, 1, 1, g+2); }
    __builtin_amdgcn_s_barrier();
    LGKM0;
    __builtin_amdgcn_s_setprio(1);
    #pragma unroll
    for (int mi = 0; mi < 4; ++mi)
      #pragma unroll
      for (int ni = 0; ni < 2; ++ni) {
        MFMA16(acc[mi+4][ni], aR[mi][0], bR[ni][0]);
        MFMA16(acc[mi+4][ni], aR[mi][1], bR[ni][1]);
      }
    __builtin_amdgcn_s_setprio(0);
    __builtin_amdgcn_s_barrier();
    // phase 4
    if (g + 2 < nt) { STG(b, 1, 2, g+2); STG(b, 1, 3, g+2); }
    __builtin_amdgcn_s_setprio(1);
    #pragma unroll
    for (int mi = 0; mi < 4; ++mi)
      #pragma unroll
      for (int ni = 2; ni < 4; ++ni) {
        MFMA16(acc[mi+4][ni], aR[mi][0], bR[ni][0]);
        MFMA16(acc[mi+4][ni], aR[mi][1], bR[ni][1]);
      }
    __builtin_amdgcn_s_setprio(0);
    if (g + 1 < nt) {
      if (g + 2 < nt) asm volatile("s_waitcnt vmcnt(6)" ::: "memory");
      else            asm volatile("s_waitcnt vmcnt(0)" ::: "memory");
    }
    __builtin_amdgcn_s_barrier();
  }

  const float* bz = bias ? (bias + (long long)z * sBias) : nullptr;
  #pragma unroll
  for (int mi = 0; mi < 8; ++mi) {
    const int row = bm + wr*128 + mi*16 + lk*4;
    #pragma unroll
    for (int ni = 0; ni < 4; ++ni) {
      const int col = bn + wc*64 + ni*16 + lr;
      const float bval = bz ? bz[col] : 0.f;
      #pragma unroll
      for (int r = 0; r < 4; ++r) {
        float val = acc[mi][ni][r] * scale + bval;
        if (OUT_BF16)
          ((short*)Cv)[(long long)z*sC + (long long)(row + r) * N + col] = f2bf(val);
        else
          ((float*)Cv)[(long long)z*sC + (long long)(row + r) * N + col] = val;
      }
    }
  }
  #undef STG
  #undef RDA
  #undef RDB
}

// ============================================================================
// 256x128 GEMM, 3-buffer ring, stage-distance 2, ONE barrier per K-tile.
// Wave layout (4,2): per-wave 64x64, acc[4][4]. Proven R4 template.
// ============================================================================
template<int OUT_BF16, int BIAS_ROW>
__global__ __launch_bounds__(512, 2) void gemm4_k(const short* __restrict__ A,
    const short* __restrict__ Bt, void* __restrict__ Cv,
    const float* __restrict__ bias,
    int K, int lda, int ldb, int ldc,
    long long sA, long long sB, long long sC, long long sBias,
    float scale, int gxs, int gys)
{
  __shared__ __align__(16) short lds[3][24576];  // per buf: A [0,16384) B [16384,24576)
  XCD_DECODE(gxs, gys);
  A  += (long long)z * sA;
  Bt += (long long)z * sB;
  const int bm = byi * 256;
  const int bn = bxi * 128;
  const int tid  = threadIdx.x;
  const int w    = tid >> 6, lane = tid & 63;
  const int wr   = w >> 1,   wc   = w & 1;
  const int lr   = lane & 15, lk  = lane >> 4;

  const int rsw0 = ((lk    ) ^ (lr & 7)) * 8;
  const int rsw1 = ((lk + 4) ^ (lr & 7)) * 8;
  const int srow = w * 8 + (lane >> 3);
  const int swc  = ((lane & 7) ^ ((lane >> 3) & 7)) * 8;
  const short* gA[4]; const short* gB[2];
  #pragma unroll
  for (int i = 0; i < 4; ++i)
    gA[i] = A + (long long)(bm + i*64 + srow) * lda + swc;
  #pragma unroll
  for (int i = 0; i < 2; ++i)
    gB[i] = Bt + (long long)(bn + i*64 + srow) * ldb + swc;

  #define STGA(buf, i, kt) \
    __builtin_amdgcn_global_load_lds((gas1_t)(gA[i] + (long long)(kt)*64), \
        (las3_t)&lds[buf][(i)*4096 + w*512], 16, 0, 0)
  #define STGB(buf, i, kt) \
    __builtin_amdgcn_global_load_lds((gas1_t)(gB[i] + (long long)(kt)*64), \
        (las3_t)&lds[buf][16384 + (i)*4096 + w*512], 16, 0, 0)
  #define RDA4(buf, mi, ks) (*(const short8*)&lds[buf][(wr*64 + (mi)*16 + lr)*64 + ((ks) ? rsw1 : rsw0)])
  #define RDB4(buf, ni, ks) (*(const short8*)&lds[buf][16384 + (wc*64 + (ni)*16 + lr)*64 + ((ks) ? rsw1 : rsw0)])

  f32x4 acc[4][4] = {};
  const int nt = K >> 6;

  STGA(0, 0, 0); STGA(0, 2, 0); STGB(0, 0, 0);
  STGB(0, 1, 0); STGA(0, 1, 0); STGA(0, 3, 0);
  STGA(1, 0, 1); STGA(1, 2, 1); STGB(1, 0, 1);
  STGB(1, 1, 1); STGA(1, 1, 1); STGA(1, 3, 1);
  asm volatile("s_waitcnt vmcnt(6)" ::: "memory");
  __builtin_amdgcn_s_barrier();

  int b = 0, nb = 2;
  for (int g = 0; g < nt; ++g) {
    short8 aR[4], bR[4];
    // ---- half 1: ks = 0 ----
    #pragma unroll
    for (int mi = 0; mi < 4; ++mi) aR[mi] = RDA4(b, mi, 0);
    #pragma unroll
    for (int ni = 0; ni < 4; ++ni) bR[ni] = RDB4(b, ni, 0);
    if (g + 2 < nt) { STGA(nb, 0, g+2); STGA(nb, 2, g+2); STGB(nb, 0, g+2); }
    LGKM0;
    __builtin_amdgcn_s_setprio(1);
    #pragma unroll
    for (int mi = 0; mi < 4; ++mi)
      #pragma unroll
      for (int ni = 0; ni < 4; ++ni)
        MFMA16(acc[mi][ni], aR[mi], bR[ni]);
    __builtin_amdgcn_s_setprio(0);
    // ---- half 2: ks = 1 ----
    #pragma unroll
    for (int mi = 0; mi < 4; ++mi) aR[mi] = RDA4(b, mi, 1);
    #pragma unroll
    for (int ni = 0; ni < 4; ++ni) bR[ni] = RDB4(b, ni, 1);
    if (g + 2 < nt) { STGB(nb, 1, g+2); STGA(nb, 1, g+2); STGA(nb, 3, g+2); }
    LGKM0;
    __builtin_amdgcn_s_setprio(1);
    #pragma unroll
    for (int mi = 0; mi < 4; ++mi)
      #pragma unroll
      for (int ni = 0; ni < 4; ++ni)
        MFMA16(acc[mi][ni], aR[mi], bR[ni]);
    __builtin_amdgcn_s_setprio(0);
    if (g + 2 < nt)      asm volatile("s_waitcnt vmcnt(6)" ::: "memory");
    else if (g + 1 < nt) asm volatile("s_waitcnt vmcnt(0)" ::: "memory");
    __builtin_amdgcn_s_barrier();
    b  = (b  == 2) ? 0 : b  + 1;
    nb = (nb == 2) ? 0 : nb + 1;
  }

  const float* bz = bias;
  #pragma unroll
  for (int mi = 0; mi < 4; ++mi) {
    const int row = bm + wr*64 + mi*16 + lk*4;
    #pragma unroll
    for (int ni = 0; ni < 4; ++ni) {
      const int col = bn + wc*64 + ni*16 + lr;
      const float bcol = (bz && !BIAS_ROW) ? bz[(long long)z*sBias + col] : 0.f;
      #pragma unroll
      for (int r = 0; r < 4; ++r) {
        float bval = BIAS_ROW ? bz[row + r] : bcol;
        float val = acc[mi][ni][r] * scale + bval;
        if (OUT_BF16)
          ((short*)Cv)[(long long)z*sC + (long long)(row + r) * ldc + col] = f2bf(val);
        else
          ((float*)Cv)[(long long)z*sC + (long long)(row + r) * ldc + col] = val;
      }
    }
  }
  #undef STGA
  #undef STGB
  #undef RDA4
  #undef RDB4
}

// ============================================================================
// gemm4 variant: A-side f32 with fused bf16 convert (reg-staged A).
// C[z] = (Az f32 [M,K]) @ (Bt bf16 [N,K])^T + bias[col], z in {0,1} selects
// A0p/A1p and Bt/bias offsets. Staging: f32 loads issued one half EARLY,
// cvt+ds_write one half LATER into the 3-buffer ring; compiler's exact data-dep
// vmcnt waits at the cvt points also drain the older STGBs one tile ahead of
// their readers (FIFO-verified, robust to within-half reorder). ds_writes
// drain at LGKM0 before MFMA; tail tiles use vmcnt(0) guard.
// ============================================================================
__global__ __launch_bounds__(512, 2) void gemm4_af32_k(
    const float* __restrict__ A0p, const float* __restrict__ A1p,
    const short* __restrict__ Bt, short* __restrict__ C,
    const float* __restrict__ bias,
    int K, int lda, int ldb, int ldc,
    long long sB, long long sC, long long sBias,
    float scale, int gxs, int gys)
{
  __shared__ __align__(16) short lds[3][24576];
  XCD_DECODE(gxs, gys);
  const float* Af = z ? A1p : A0p;
  const int bm = byi * 256;
  const int bn = bxi * 128;
  const int tid  = threadIdx.x;
  const int w    = tid >> 6, lane = tid & 63;
  const int wr   = w >> 1,   wc   = w & 1;
  const int lr   = lane & 15, lk  = lane >> 4;

  const int rsw0 = ((lk    ) ^ (lr & 7)) * 8;
  const int rsw1 = ((lk + 4) ^ (lr & 7)) * 8;
  const int srow = w * 8 + (lane >> 3);
  const int swc  = ((lane & 7) ^ ((lane >> 3) & 7)) * 8;
  const float* gAf[4]; const short* gB[2];
  #pragma unroll
  for (int i = 0; i < 4; ++i)
    gAf[i] = Af + (long long)(bm + i*64 + srow) * lda + swc;
  #pragma unroll
  for (int i = 0; i < 2; ++i)
    gB[i] = Bt + (long long)z * sB + (long long)(bn + i*64 + srow) * ldb + swc;

  float4 la[4][2];
  #define LAF(i, kt) do { const float* p_ = gAf[i] + (long long)(kt)*64; \
      la[i][0] = *(const float4*)p_; la[i][1] = *(const float4*)(p_ + 4); } while (0)
  #define WRA(buf, i) do { short8 s_; \
      s_[0]=f2bf(la[i][0].x); s_[1]=f2bf(la[i][0].y); s_[2]=f2bf(la[i][0].z); s_[3]=f2bf(la[i][0].w); \
      s_[4]=f2bf(la[i][1].x); s_[5]=f2bf(la[i][1].y); s_[6]=f2bf(la[i][1].z); s_[7]=f2bf(la[i][1].w); \
      *(short8*)&lds[buf][(i)*4096 + w*512 + lane*8] = s_; } while (0)
  #define STGBf(buf, i, kt) \
    __builtin_amdgcn_global_load_lds((gas1_t)(gB[i] + (long long)(kt)*64), \
        (las3_t)&lds[buf][16384 + (i)*4096 + w*512], 16, 0, 0)
  #define RDAf(buf, mi, ks) (*(const short8*)&lds[buf][(wr*64 + (mi)*16 + lr)*64 + ((ks) ? rsw1 : rsw0)])
  #define RDBf(buf, ni, ks) (*(const short8*)&lds[buf][16384 + (wc*64 + (ni)*16 + lr)*64 + ((ks) ? rsw1 : rsw0)])

  f32x4 acc[4][4] = {};
  const int nt = K >> 6;

  // prologue: tiles 0,1 -> bufs 0,1; la[1],la[3] exit holding tile-1 data
  LAF(0, 0); LAF(2, 0); STGBf(0, 0, 0);
  LAF(1, 0); LAF(3, 0); STGBf(0, 1, 0);
  WRA(0, 0); WRA(0, 2);
  WRA(0, 1); WRA(0, 3);
  LAF(0, 1); LAF(2, 1); STGBf(1, 0, 1);
  WRA(1, 0); WRA(1, 2);
  LAF(1, 1); LAF(3, 1); STGBf(1, 1, 1);
  LGKM0;
  __builtin_amdgcn_s_barrier();

  int b = 0, nb = 2, pb = 1;  // pb = buf(g+1)
  for (int g = 0; g < nt; ++g) {
    short8 aR[4], bR[4];
    // ---- half 1 (ks0): consume A1,A3(g+1); issue A0,A2(g+2) + B0(g+2) ----
    #pragma unroll
    for (int mi = 0; mi < 4; ++mi) aR[mi] = RDAf(b, mi, 0);
    #pragma unroll
    for (int ni = 0; ni < 4; ++ni) bR[ni] = RDBf(b, ni, 0);
    if (g + 2 < nt) { LAF(0, g+2); LAF(2, g+2); STGBf(nb, 0, g+2); }
    if (g + 1 < nt) { WRA(pb, 1); WRA(pb, 3); }
    LGKM0;
    __builtin_amdgcn_s_setprio(1);
    #pragma unroll
    for (int mi = 0; mi < 4; ++mi)
      #pragma unroll
      for (int ni = 0; ni < 4; ++ni)
        MFMA16(acc[mi][ni], aR[mi], bR[ni]);
    __builtin_amdgcn_s_setprio(0);
    // ---- half 2 (ks1): issue A1,A3(g+2) + B1(g+2); write A0,A2(g+2) ----
    #pragma unroll
    for (int mi = 0; mi < 4; ++mi) aR[mi] = RDAf(b, mi, 1);
    #pragma unroll
    for (int ni = 0; ni < 4; ++ni) bR[ni] = RDBf(b, ni, 1);
    if (g + 2 < nt) { LAF(1, g+2); LAF(3, g+2); STGBf(nb, 1, g+2);
                      WRA(nb, 0); WRA(nb, 2); }
    LGKM0;
    __builtin_amdgcn_s_setprio(1);
    #pragma unroll
    for (int mi = 0; mi < 4; ++mi)
      #pragma unroll
      for (int ni = 0; ni < 4; ++ni)
        MFMA16(acc[mi][ni], aR[mi], bR[ni]);
    __builtin_amdgcn_s_setprio(0);
    if (g + 2 >= nt) asm volatile("s_waitcnt vmcnt(0)" ::: "memory");
    __builtin_amdgcn_s_barrier();
    b  = (b  == 2) ? 0 : b  + 1;
    nb = (nb == 2) ? 0 : nb + 1;
    pb = (pb == 2) ? 0 : pb + 1;
  }

  const float* bz = bias + (long long)z * sBias;
  #pragma unroll
  for (int mi = 0; mi < 4; ++mi) {
    const int row = bm + wr*64 + mi*16 + lk*4;
    #pragma unroll
    for (int ni = 0; ni < 4; ++ni) {
      const int col = bn + wc*64 + ni*16 + lr;
      const float bval = bz[col];
      #pragma unroll
      for (int r = 0; r < 4; ++r)
        C[(long long)z*sC + (long long)(row + r) * ldc + col] = f2bf(acc[mi][ni][r] * scale + bval);
    }
  }
  #undef LAF
  #undef WRA
  #undef STGBf
  #undef RDAf
  #undef RDBf
}

// ============================================================================
// gemm4 variant: B-side f32 with fused bf16 convert (reg-staged B), row-bias.
// C = (A bf16 [M,K]) @ (Btf f32 [N,K])^T + bias[row]. Same staging discipline
// as gemm4_af32 with A/B roles mirrored (A via gload_lds, B reg-staged:
// loads in half1, cvt+write in half2, same tile distance 2).
// ============================================================================
__global__ __launch_bounds__(512, 2) void gemm4_bf32_k(
    const short* __restrict__ A, const float* __restrict__ Btf,
    short* __restrict__ C, const float* __restrict__ bias,
    int K, int lda, int ldb, int ldc, float scale, int gxs, int gys)
{
  __shared__ __align__(16) short lds[3][24576];
  XCD_DECODE(gxs, gys);
  (void)z;
  const int bm = byi * 256;
  const int bn = bxi * 128;
  const int tid  = threadIdx.x;
  const int w    = tid >> 6, lane = tid & 63;
  const int wr   = w >> 1,   wc   = w & 1;
  const int lr   = lane & 15, lk  = lane >> 4;

  const int rsw0 = ((lk    ) ^ (lr & 7)) * 8;
  const int rsw1 = ((lk + 4) ^ (lr & 7)) * 8;
  const int srow = w * 8 + (lane >> 3);
  const int swc  = ((lane & 7) ^ ((lane >> 3) & 7)) * 8;
  const short* gA[4]; const float* gBf[2];
  #pragma unroll
  for (int i = 0; i < 4; ++i)
    gA[i] = A + (long long)(bm + i*64 + srow) * lda + swc;
  #pragma unroll
  for (int i = 0; i < 2; ++i)
    gBf[i] = Btf + (long long)(bn + i*64 + srow) * ldb + swc;

  float4 lb[2][2];
  #define LBF(i, kt) do { const float* p_ = gBf[i] + (long long)(kt)*64; \
      lb[i][0] = *(const float4*)p_; lb[i][1] = *(const float4*)(p_ + 4); } while (0)
  #define WRB(buf, i) do { short8 s_; \
      s_[0]=f2bf(lb[i][0].x); s_[1]=f2bf(lb[i][0].y); s_[2]=f2bf(lb[i][0].z); s_[3]=f2bf(lb[i][0].w); \
      s_[4]=f2bf(lb[i][1].x); s_[5]=f2bf(lb[i][1].y); s_[6]=f2bf(lb[i][1].z); s_[7]=f2bf(lb[i][1].w); \
      *(short8*)&lds[buf][16384 + (i)*4096 + w*512 + lane*8] = s_; } while (0)
  #define STGAb(buf, i, kt) \
    __builtin_amdgcn_global_load_lds((gas1_t)(gA[i] + (long long)(kt)*64), \
        (las3_t)&lds[buf][(i)*4096 + w*512], 16, 0, 0)
  #define RDAb(buf, mi, ks) (*(const short8*)&lds[buf][(wr*64 + (mi)*16 + lr)*64 + ((ks) ? rsw1 : rsw0)])
  #define RDBb(buf, ni, ks) (*(const short8*)&lds[buf][16384 + (wc*64 + (ni)*16 + lr)*64 + ((ks) ? rsw1 : rsw0)])

  f32x4 acc[4][4] = {};
  const int nt = K >> 6;

  // prologue: tiles 0,1
  STGAb(0, 0, 0); STGAb(0, 2, 0); LBF(0, 0); LBF(1, 0); STGAb(0, 1, 0); STGAb(0, 3, 0);
  WRB(0, 0); WRB(0, 1);
  STGAb(1, 0, 1); STGAb(1, 2, 1); LBF(0, 1); LBF(1, 1); STGAb(1, 1, 1); STGAb(1, 3, 1);
  WRB(1, 0); WRB(1, 1);
  LGKM0;
  __builtin_amdgcn_s_barrier();

  int b = 0, nb = 2;
  for (int g = 0; g < nt; ++g) {
    short8 aR[4], bR[4];
    // ---- half 1 (ks0): stage A0,A2(g+2); issue B loads(g+2) ----
    #pragma unroll
    for (int mi = 0; mi < 4; ++mi) aR[mi] = RDAb(b, mi, 0);
    #pragma unroll
    for (int ni = 0; ni < 4; ++ni) bR[ni] = RDBb(b, ni, 0);
    if (g + 2 < nt) { STGAb(nb, 0, g+2); STGAb(nb, 2, g+2); LBF(0, g+2); LBF(1, g+2); }
    LGKM0;
    __builtin_amdgcn_s_setprio(1);
    #pragma unroll
    for (int mi = 0; mi < 4; ++mi)
      #pragma unroll
      for (int ni = 0; ni < 4; ++ni)
        MFMA16(acc[mi][ni], aR[mi], bR[ni]);
    __builtin_amdgcn_s_setprio(0);
    // ---- half 2 (ks1): stage A1,A3(g+2); cvt+write B(g+2) ----
    #pragma unroll
    for (int mi = 0; mi < 4; ++mi) aR[mi] = RDAb(b, mi, 1);
    #pragma unroll
    for (int ni = 0; ni < 4; ++ni) bR[ni] = RDBb(b, ni, 1);
    if (g + 2 < nt) { STGAb(nb, 1, g+2); STGAb(nb, 3, g+2); WRB(nb, 0); WRB(nb, 1); }
    LGKM0;
    __builtin_amdgcn_s_setprio(1);
    #pragma unroll
    for (int mi = 0; mi < 4; ++mi)
      #pragma unroll
      for (int ni = 0; ni < 4; ++ni)
        MFMA16(acc[mi][ni], aR[mi], bR[ni]);
    __builtin_amdgcn_s_setprio(0);
    if (g + 2 >= nt) asm volatile("s_waitcnt vmcnt(0)" ::: "memory");
    __builtin_amdgcn_s_barrier();
    b  = (b  == 2) ? 0 : b  + 1;
    nb = (nb == 2) ? 0 : nb + 1;
  }

  #pragma unroll
  for (int mi = 0; mi < 4; ++mi) {
    const int row = bm + wr*64 + mi*16 + lk*4;
    #pragma unroll
    for (int ni = 0; ni < 4; ++ni) {
      const int col = bn + wc*64 + ni*16 + lr;
      #pragma unroll
      for (int r = 0; r < 4; ++r)
        C[(long long)(row + r) * ldc + col] = f2bf(acc[mi][ni][r] * scale + bias[row + r]);
    }
  }
  #undef LBF
  #undef WRB
  #undef STGAb
  #undef RDAb
  #undef RDBb
}

extern "C" void kernel_launch(void* const* d_in, const int* in_sizes, int n_in,
                              void* d_out, int out_size, void* d_ws, size_t ws_size,
                              hipStream_t stream) {
  const float* q  = (const float*)d_in[0];
  const float* k  = (const float*)d_in[1];
  const float* v  = (const float*)d_in[2];
  const float* Wq = (const float*)d_in[4];
  const float* bq = (const float*)d_in[5];
  const float* Wk = (const float*)d_in[6];
  const float* bk = (const float*)d_in[7];
  const float* Wv = (const float*)d_in[8];
  const float* bv = (const float*)d_in[9];
  const float* Wo = (const float*)d_in[10];
  const float* bo = (const float*)d_in[11];

  // ws layout (bytes), peak ~109.1 MB:
  char* w = (char*)d_ws;
  short* Wt     = (short*)(w);                  // [4][1024][1024] bf16 (W^T)   8,388,608
  float* biasb  = (float*)(w + 8388608);        // [4][1024] f32                   16,384
  short* QKV    = (short*)(w + 8404992);        // Q,K bf16 [2][4,2048,1024]   33,554,432
  short* P      = (short*)(w + 41959424);       // scores/P bf16 [4,2048,2048] 33,554,432
  short* Vt     = (short*)(w + 75513856);       // [1024][8192] bf16            16,777,216
  short* xt     = (short*)(w + 92291072);       // [4][1024][2048] bf16         16,777,216

  short* Qp = QKV;
  short* Kp = QKV + 8388608LL;

  // 1) weights + biases to bf16/contiguous
  bias_gather_k<<<dim3(16), 256, 0, stream>>>(bq, bk, bv, bo, biasb);
  wt_cvt_k<<<dim3(32,32,4), dim3(32,8), 0, stream>>>(Wq, Wk, Wv, Wo, Wt);

  // 2a) q,k projections with fused f32->bf16 A: grid 8(N) x 32(M) x 2(z) = 512
  gemm4_af32_k<<<512, 512, 0, stream>>>(q, k, Wt, QKV, biasb,
      1024, 1024, 1024, 1024, 1048576LL, 8388608LL, 1024LL, 1.0f, 3, 5);

  // 2b) V projection, transposed output, fused f32->bf16 B:
  //     Vt[d, bs] = Wv^T @ v^T + bv[d]; grid 64(N) x 4(M) = 256
  gemm4_bf32_k<<<256, 512, 0, stream>>>(Wt + 2097152LL, v, Vt, biasb + 2048,
      1024, 1024, 1024, 8192, 1.0f, 6, 2);

  // 3) scores = Q @ K^T / 32 -> bf16 P (256 blocks = 1 round)
  gemm8_k<1><<<256, 512, 0, stream>>>(Qp, Kp, P, nullptr,
      2048, 2048, 1024, 2097152LL, 2097152LL, 4194304LL, 0LL, 0.03125f, 3, 3);

  // 4) P = softmax_rows(P) in place
  softmax_bf_k<<<dim3(8192), 256, 0, stream>>>(P);

  // 5) xt[d, q] = Vt[d,:] . P[q,:]  (A = Vt + z*2048 cols, lda=8192)
  gemm4_k<1,0><<<256, 512, 0, stream>>>(Vt, P, xt, nullptr,
      2048, 8192, 2048, 2048, 2048LL, 4194304LL, 2097152LL, 0LL, 1.0f, 4, 2);

  // 6) out = reshape(xt) @ Wo + bo; xt reinterpreted [2048][1024] row-major per z
  gemm4_k<0,0><<<256, 512, 0, stream>>>(xt, Wt + 3145728LL, (float*)d_out,
      biasb + 3072, 1024, 1024, 1024, 1024, 2097152LL, 0LL, 2097152LL, 0LL, 1.0f, 3, 3);
}

// Round 7
// 215.315 us; speedup vs baseline: 1.0652x; 1.0652x over previous
//
#include <hip/hip_runtime.h>
#include <hip/hip_bf16.h>
#include <stdint.h>

typedef __attribute__((ext_vector_type(8))) short short8;
typedef __attribute__((ext_vector_type(4))) float f32x4;
typedef __attribute__((ext_vector_type(16))) float f32x16;
typedef const __attribute__((address_space(1))) uint32_t* gas1_t;
typedef __attribute__((address_space(3))) uint32_t* las3_t;

__device__ __forceinline__ short f2bf(float f) {
  uint32_t u = __builtin_bit_cast(uint32_t, f);
  u += 0x7fffu + ((u >> 16) & 1u);
  return (short)(u >> 16);
}
__device__ __forceinline__ float bf2f(short s) {
  return __builtin_bit_cast(float, ((uint32_t)(uint16_t)s) << 16);
}

// ---- convert q,k,v f32 -> bf16 (z selects tensor) ----
__global__ __launch_bounds__(256) void cvt_qkv_k(const float* __restrict__ q,
    const float* __restrict__ k, const float* __restrict__ v,
    short* __restrict__ dst) {
  const long long n = 8388608LL;
  const float* src = (blockIdx.z == 0) ? q : (blockIdx.z == 1) ? k : v;
  long long i = ((long long)blockIdx.x * 256 + threadIdx.x) * 8;
  float4 a = *(const float4*)(src + i);
  float4 b = *(const float4*)(src + i + 4);
  short8 o;
  o[0]=f2bf(a.x); o[1]=f2bf(a.y); o[2]=f2bf(a.z); o[3]=f2bf(a.w);
  o[4]=f2bf(b.x); o[5]=f2bf(b.y); o[6]=f2bf(b.z); o[7]=f2bf(b.w);
  *(short8*)(dst + (long long)blockIdx.z * n + i) = o;
}

// ---- gather the 4 bias vectors into one contiguous buffer ----
__global__ __launch_bounds__(256) void bias_gather_k(const float* b0, const float* b1,
    const float* b2, const float* b3, float* __restrict__ dst) {
  int i = blockIdx.x * 256 + threadIdx.x;
  if (i >= 4096) return;
  int z = i >> 10, j = i & 1023;
  const float* s = (z==0)?b0:(z==1)?b1:(z==2)?b2:b3;
  dst[i] = s[j];
}

// ---- weights: W[K=1024,N=1024] f32 -> Wt[N,K] bf16 (z selects weight) ----
__global__ __launch_bounds__(256) void wt_cvt_k(const float* w0, const float* w1,
    const float* w2, const float* w3, short* __restrict__ dst) {
  __shared__ float t[32][33];
  const float* W = (blockIdx.z==0)?w0:(blockIdx.z==1)?w1:(blockIdx.z==2)?w2:w3;
  short* D = dst + (long long)blockIdx.z * 1048576LL;
  int n0 = blockIdx.x * 32, k0 = blockIdx.y * 32;
  int tx = threadIdx.x, ty = threadIdx.y;
  #pragma unroll
  for (int i = 0; i < 4; ++i)
    t[ty + 8*i][tx] = W[(long long)(k0 + ty + 8*i) * 1024 + n0 + tx];
  __syncthreads();
  #pragma unroll
  for (int i = 0; i < 4; ++i)
    D[(long long)(n0 + ty + 8*i) * 1024 + k0 + tx] = f2bf(t[tx][ty + 8*i]);
}

// ---- in-place row softmax on bf16 [rows,2048] ----
__global__ __launch_bounds__(256) void softmax_bf_k(short* __restrict__ SP) {
  short* sp = SP + (long long)blockIdx.x * 2048;
  const int t = threadIdx.x;
  short8 sv = *(const short8*)(sp + t*8);
  float v[8];
  #pragma unroll
  for (int j = 0; j < 8; ++j) v[j] = bf2f(sv[j]);
  float m = v[0];
  #pragma unroll
  for (int j = 1; j < 8; ++j) m = fmaxf(m, v[j]);
  #pragma unroll
  for (int off = 32; off > 0; off >>= 1) m = fmaxf(m, __shfl_down(m, off, 64));
  __shared__ float rmax[4], rsum[4];
  int wv = t >> 6, ln = t & 63;
  if (ln == 0) rmax[wv] = m;
  __syncthreads();
  m = fmaxf(fmaxf(rmax[0], rmax[1]), fmaxf(rmax[2], rmax[3]));
  float e[8], sum = 0.f;
  #pragma unroll
  for (int j = 0; j < 8; ++j) { e[j] = exp2f((v[j] - m) * 1.44269504f); sum += e[j]; }
  #pragma unroll
  for (int off = 32; off > 0; off >>= 1) sum += __shfl_down(sum, off, 64);
  if (ln == 0) rsum[wv] = sum;
  __syncthreads();
  float inv = 1.0f / (rsum[0] + rsum[1] + rsum[2] + rsum[3]);
  short8 o;
  #pragma unroll
  for (int j = 0; j < 8; ++j) o[j] = f2bf(e[j] * inv);
  *(short8*)(sp + t*8) = o;
}

#define MFMA16(d, a_, b_) d = __builtin_amdgcn_mfma_f32_16x16x32_bf16(a_, b_, d, 0, 0, 0)
#define MFMA32(d, a_, b_) d = __builtin_amdgcn_mfma_f32_32x32x16_bf16(a_, b_, d, 0, 0, 0)
#define LGKM0 do { asm volatile("s_waitcnt lgkmcnt(0)" ::: "memory"); \
                   __builtin_amdgcn_sched_barrier(0); } while (0)
// flattened 1-D grid + bijective XCD-chunked swizzle (nwg % 8 == 0 at all call sites)
#define XCD_DECODE(gxs_, gys_) \
  const int nwg = (int)gridDim.x; \
  const int wg = ((int)blockIdx.x & 7) * (nwg >> 3) + ((int)blockIdx.x >> 3); \
  const int bxi = wg & ((1 << (gxs_)) - 1); \
  const int byi = (wg >> (gxs_)) & ((1 << (gys_)) - 1); \
  const int z = wg >> ((gxs_) + (gys_));

// ============================================================================
// 256x256 8-phase GEMM (proven template + XCD swizzle). BK=64, 8 waves.
// ============================================================================
template<int OUT_BF16>
__global__ __launch_bounds__(512, 2) void gemm8_k(const short* __restrict__ A,
    const short* __restrict__ Bt, void* __restrict__ Cv,
    const float* __restrict__ bias,
    int M, int N, int K, long long sA, long long sB, long long sC,
    long long sBias, float scale, int gxs, int gys)
{
  __shared__ __align__(16) short lds[2][2][256*64];
  XCD_DECODE(gxs, gys);
  A  += (long long)z * sA;
  Bt += (long long)z * sB;
  const int bm = byi * 256;
  const int bn = bxi * 256;
  const int tid  = threadIdx.x;
  const int w    = tid >> 6, lane = tid & 63;
  const int wr   = w >> 2,   wc   = w & 3;
  const int lr   = lane & 15, lk  = lane >> 4;

  const int rsw0 = ((lk    ) ^ (lr & 7)) * 8;
  const int rsw1 = ((lk + 4) ^ (lr & 7)) * 8;
  const int srow = w * 8 + (lane >> 3);
  const int swc  = ((lane & 7) ^ ((lane >> 3) & 7)) * 8;
  const short* gA[4]; const short* gB[4];
  #pragma unroll
  for (int i = 0; i < 4; ++i) {
    gA[i] = A  + (long long)(bm + i*64 + srow) * K + swc;
    gB[i] = Bt + (long long)(bn + i*64 + srow) * K + swc;
  }

  #define STG(buf, ab, i, kt) \
    __builtin_amdgcn_global_load_lds((gas1_t)(((ab) ? gB : gA)[i] + (long long)(kt)*64), \
        (las3_t)&lds[buf][ab][(i)*4096 + w*512], 16, 0, 0)
  #define RDA(buf, mi, ks) (*(const short8*)&lds[buf][0][(wr*128 + (mi)*16 + lr)*64 + ((ks) ? rsw1 : rsw0)])
  #define RDB(buf, ni, ks) (*(const short8*)&lds[buf][1][(wc*64  + (ni)*16 + lr)*64 + ((ks) ? rsw1 : rsw0)])

  f32x4 acc[8][4] = {};
  const int nt = K >> 6;

  #pragma unroll
  for (int i = 0; i < 4; ++i) STG(0, 0, i, 0);
  #pragma unroll
  for (int i = 0; i < 4; ++i) STG(0, 1, i, 0);
  STG(1, 0, 0, 1); STG(1, 0, 2, 1);
  STG(1, 1, 0, 1); STG(1, 1, 1, 1);
  STG(1, 1, 2, 1); STG(1, 1, 3, 1);
  asm volatile("s_waitcnt vmcnt(6)" ::: "memory");
  __builtin_amdgcn_s_barrier();

  for (int g = 0; g < nt; ++g) {
    const int b = g & 1, nb = b ^ 1;
    short8 aR[4][2], bR[4][2];
    // phase 1
    #pragma unroll
    for (int mi = 0; mi < 4; ++mi) { aR[mi][0] = RDA(b, mi, 0); aR[mi][1] = RDA(b, mi, 1); }
    #pragma unroll
    for (int ni = 0; ni < 2; ++ni) { bR[ni][0] = RDB(b, ni, 0); bR[ni][1] = RDB(b, ni, 1); }
    if (g + 1 < nt) { STG(nb, 0, 1, g+1); STG(nb, 0, 3, g+1); }
    __builtin_amdgcn_s_barrier();
    LGKM0;
    __builtin_amdgcn_s_setprio(1);
    #pragma unroll
    for (int mi = 0; mi < 4; ++mi)
      #pragma unroll
      for (int ni = 0; ni < 2; ++ni) {
        MFMA16(acc[mi][ni], aR[mi][0], bR[ni][0]);
        MFMA16(acc[mi][ni], aR[mi][1], bR[ni][1]);
      }
    __builtin_amdgcn_s_setprio(0);
    __builtin_amdgcn_s_barrier();
    // phase 2
    #pragma unroll
    for (int ni = 2; ni < 4; ++ni) { bR[ni][0] = RDB(b, ni, 0); bR[ni][1] = RDB(b, ni, 1); }
    if (g + 2 < nt) { STG(b, 0, 0, g+2); STG(b, 0, 2, g+2); }
    __builtin_amdgcn_s_barrier();
    LGKM0;
    __builtin_amdgcn_s_setprio(1);
    #pragma unroll
    for (int mi = 0; mi < 4; ++mi)
      #pragma unroll
      for (int ni = 2; ni < 4; ++ni) {
        MFMA16(acc[mi][ni], aR[mi][0], bR[ni][0]);
        MFMA16(acc[mi][ni], aR[mi][1], bR[ni][1]);
      }
    __builtin_amdgcn_s_setprio(0);
    __builtin_amdgcn_s_barrier();
    // phase 3
    #pragma unroll
    for (int mi = 0; mi < 4; ++mi) { aR[mi][0] = RDA(b, mi+4, 0); aR[mi][1] = RDA(b, mi+4, 1); }
    if (g + 2 < nt) { STG(b, 1, 0, g+2); STG(b, 1, 1, g+2); }
    __builtin_amdgcn_s_barrier();
    LGKM0;
    __builtin_amdgcn_s_setprio(1);
    #pragma unroll
    for (int mi = 0; mi < 4; ++mi)
      #pragma unroll
      for (int ni = 0; ni < 2; ++ni) {
        MFMA16(acc[mi+4][ni], aR[mi][0], bR[ni][0]);
        MFMA16(acc[mi+4][ni], aR[mi][1], bR[ni][1]);
      }
    __builtin_amdgcn_s_setprio(0);
    __builtin_amdgcn_s_barrier();
    // phase 4
    if (g + 2 < nt) { STG(b, 1, 2, g+2); STG(b, 1, 3, g+2); }
    __builtin_amdgcn_s_setprio(1);
    #pragma unroll
    for (int mi = 0; mi < 4; ++mi)
      #pragma unroll
      for (int ni = 2; ni < 4; ++ni) {
        MFMA16(acc[mi+4][ni], aR[mi][0], bR[ni][0]);
        MFMA16(acc[mi+4][ni], aR[mi][1], bR[ni][1]);
      }
    __builtin_amdgcn_s_setprio(0);
    if (g + 1 < nt) {
      if (g + 2 < nt) asm volatile("s_waitcnt vmcnt(6)" ::: "memory");
      else            asm volatile("s_waitcnt vmcnt(0)" ::: "memory");
    }
    __builtin_amdgcn_s_barrier();
  }

  const float* bz = bias ? (bias + (long long)z * sBias) : nullptr;
  #pragma unroll
  for (int mi = 0; mi < 8; ++mi) {
    const int row = bm + wr*128 + mi*16 + lk*4;
    #pragma unroll
    for (int ni = 0; ni < 4; ++ni) {
      const int col = bn + wc*64 + ni*16 + lr;
      const float bval = bz ? bz[col] : 0.f;
      #pragma unroll
      for (int r = 0; r < 4; ++r) {
        float val = acc[mi][ni][r] * scale + bval;
        if (OUT_BF16)
          ((short*)Cv)[(long long)z*sC + (long long)(row + r) * N + col] = f2bf(val);
        else
          ((float*)Cv)[(long long)z*sC + (long long)(row + r) * N + col] = val;
      }
    }
  }
  #undef STG
  #undef RDA
  #undef RDB
}

// ============================================================================
// 256x128 GEMM, 3-buffer ring, stage-distance 2, ONE barrier per K-tile —
// R4-proven staging/sync, inner loop switched to mfma_f32_32x32x16_bf16.
// Wave layout (4,2): per-wave 64x64 out = acc f32x16[2][2]. Per K-tile per
// wave: 16 ds_read_b128 (was 24) + 16 MFMA-32x32 (was 32 MFMA-16x16).
// A/B frag: row/col = lane&31, k = (lane>>5)*8 + j (ks selects 16-wide K
// slice: granule = ks*2 + (lane>>5), XOR-swizzled by row&7).
// C/D frag (HW-verified m74/m101): col=lane&31, row=(r&3)+8*(r>>2)+4*(lane>>5).
// ============================================================================
template<int OUT_BF16, int BIAS_ROW>
__global__ __launch_bounds__(512, 2) void gemm4_k(const short* __restrict__ A,
    const short* __restrict__ Bt, void* __restrict__ Cv,
    const float* __restrict__ bias,
    int K, int lda, int ldb, int ldc,
    long long sA, long long sB, long long sC, long long sBias,
    float scale, int gxs, int gys)
{
  __shared__ __align__(16) short lds[3][24576];  // per buf: A [0,16384) B [16384,24576)
  XCD_DECODE(gxs, gys);
  A  += (long long)z * sA;
  Bt += (long long)z * sB;
  const int bm = byi * 256;
  const int bn = bxi * 128;
  const int tid  = threadIdx.x;
  const int w    = tid >> 6, lane = tid & 63;
  const int wr   = w >> 1,   wc   = w & 1;
  const int l31  = lane & 31, l5 = lane >> 5, rq = lane & 7;

  const int srow = w * 8 + (lane >> 3);
  const int swc  = ((lane & 7) ^ ((lane >> 3) & 7)) * 8;
  const short* gA[4]; const short* gB[2];
  #pragma unroll
  for (int i = 0; i < 4; ++i)
    gA[i] = A + (long long)(bm + i*64 + srow) * lda + swc;
  #pragma unroll
  for (int i = 0; i < 2; ++i)
    gB[i] = Bt + (long long)(bn + i*64 + srow) * ldb + swc;

  #define STGA(buf, i, kt) \
    __builtin_amdgcn_global_load_lds((gas1_t)(gA[i] + (long long)(kt)*64), \
        (las3_t)&lds[buf][(i)*4096 + w*512], 16, 0, 0)
  #define STGB(buf, i, kt) \
    __builtin_amdgcn_global_load_lds((gas1_t)(gB[i] + (long long)(kt)*64), \
        (las3_t)&lds[buf][16384 + (i)*4096 + w*512], 16, 0, 0)
  #define RDA32(buf, mi, ks) (*(const short8*)&lds[buf][(wr*64 + (mi)*32 + l31)*64 + ((((ks)*2 + l5) ^ rq))*8])
  #define RDB32(buf, ni, ks) (*(const short8*)&lds[buf][16384 + (wc*64 + (ni)*32 + l31)*64 + ((((ks)*2 + l5) ^ rq))*8])

  f32x16 acc[2][2] = {};
  const int nt = K >> 6;

  STGA(0, 0, 0); STGA(0, 2, 0); STGB(0, 0, 0);
  STGB(0, 1, 0); STGA(0, 1, 0); STGA(0, 3, 0);
  STGA(1, 0, 1); STGA(1, 2, 1); STGB(1, 0, 1);
  STGB(1, 1, 1); STGA(1, 1, 1); STGA(1, 3, 1);
  asm volatile("s_waitcnt vmcnt(6)" ::: "memory");
  __builtin_amdgcn_s_barrier();

  int b = 0, nb = 2;
  for (int g = 0; g < nt; ++g) {
    short8 aR[2][2], bR[2][2];
    // ---- half 1: ks = 0,1 ----
    #pragma unroll
    for (int mi = 0; mi < 2; ++mi) { aR[mi][0] = RDA32(b, mi, 0); aR[mi][1] = RDA32(b, mi, 1); }
    #pragma unroll
    for (int ni = 0; ni < 2; ++ni) { bR[ni][0] = RDB32(b, ni, 0); bR[ni][1] = RDB32(b, ni, 1); }
    if (g + 2 < nt) { STGA(nb, 0, g+2); STGA(nb, 2, g+2); STGB(nb, 0, g+2); }
    LGKM0;
    __builtin_amdgcn_s_setprio(1);
    #pragma unroll
    for (int mi = 0; mi < 2; ++mi)
      #pragma unroll
      for (int ni = 0; ni < 2; ++ni) {
        MFMA32(acc[mi][ni], aR[mi][0], bR[ni][0]);
        MFMA32(acc[mi][ni], aR[mi][1], bR[ni][1]);
      }
    __builtin_amdgcn_s_setprio(0);
    // ---- half 2: ks = 2,3 ----
    #pragma unroll
    for (int mi = 0; mi < 2; ++mi) { aR[mi][0] = RDA32(b, mi, 2); aR[mi][1] = RDA32(b, mi, 3); }
    #pragma unroll
    for (int ni = 0; ni < 2; ++ni) { bR[ni][0] = RDB32(b, ni, 2); bR[ni][1] = RDB32(b, ni, 3); }
    if (g + 2 < nt) { STGB(nb, 1, g+2); STGA(nb, 1, g+2); STGA(nb, 3, g+2); }
    LGKM0;
    __builtin_amdgcn_s_setprio(1);
    #pragma unroll
    for (int mi = 0; mi < 2; ++mi)
      #pragma unroll
      for (int ni = 0; ni < 2; ++ni) {
        MFMA32(acc[mi][ni], aR[mi][0], bR[ni][0]);
        MFMA32(acc[mi][ni], aR[mi][1], bR[ni][1]);
      }
    __builtin_amdgcn_s_setprio(0);
    if (g + 2 < nt)      asm volatile("s_waitcnt vmcnt(6)" ::: "memory");
    else if (g + 1 < nt) asm volatile("s_waitcnt vmcnt(0)" ::: "memory");
    __builtin_amdgcn_s_barrier();
    b  = (b  == 2) ? 0 : b  + 1;
    nb = (nb == 2) ? 0 : nb + 1;
  }

  const float* bz = bias;
  #pragma unroll
  for (int mi = 0; mi < 2; ++mi) {
    #pragma unroll
    for (int ni = 0; ni < 2; ++ni) {
      const int col = bn + wc*64 + ni*32 + l31;
      const float bcol = (bz && !BIAS_ROW) ? bz[(long long)z*sBias + col] : 0.f;
      #pragma unroll
      for (int r = 0; r < 16; ++r) {
        const int row = bm + wr*64 + mi*32 + (r&3) + 8*(r>>2) + 4*l5;
        float bval = BIAS_ROW ? bz[row] : bcol;
        float val = acc[mi][ni][r] * scale + bval;
        if (OUT_BF16)
          ((short*)Cv)[(long long)z*sC + (long long)row * ldc + col] = f2bf(val);
        else
          ((float*)Cv)[(long long)z*sC + (long long)row * ldc + col] = val;
      }
    }
  }
  #undef STGA
  #undef STGB
  #undef RDA32
  #undef RDB32
}

extern "C" void kernel_launch(void* const* d_in, const int* in_sizes, int n_in,
                              void* d_out, int out_size, void* d_ws, size_t ws_size,
                              hipStream_t stream) {
  const float* q  = (const float*)d_in[0];
  const float* k  = (const float*)d_in[1];
  const float* v  = (const float*)d_in[2];
  const float* Wq = (const float*)d_in[4];
  const float* bq = (const float*)d_in[5];
  const float* Wk = (const float*)d_in[6];
  const float* bk = (const float*)d_in[7];
  const float* Wv = (const float*)d_in[8];
  const float* bv = (const float*)d_in[9];
  const float* Wo = (const float*)d_in[10];
  const float* bo = (const float*)d_in[11];

  // ws layout (bytes), peak ~142.6 MB (R4 layout):
  char* w = (char*)d_ws;
  short* Wt     = (short*)(w);                  // [4][1024][1024] bf16 (W^T)   8,388,608
  float* biasb  = (float*)(w + 8388608);        // [4][1024] f32                   16,384
  short* QKV    = (short*)(w + 8404992);        // Q,K bf16 [2][4,2048,1024]   16,777,216x2
  short* qkvbf  = (short*)(w + 58736640);       // q,k,v bf16, die after projections
  short* P      = (short*)(w + 58736640);       // scores/P bf16 [4,2048,2048] (reuses q,k part)
  short* Vt     = (short*)(w + 109068288);      // [1024][8192] bf16            16,777,216
  short* xt     = (short*)(w + 125845504);      // [4][1024][2048] bf16         16,777,216

  short* Qp = QKV;
  short* Kp = QKV + 8388608LL;
  short* vbf = qkvbf + 16777216LL;              // byte 92291072.. (outside P)

  // 1) convert inputs + weights, gather biases
  cvt_qkv_k<<<dim3(4096,1,3), 256, 0, stream>>>(q, k, v, qkvbf);
  bias_gather_k<<<dim3(16), 256, 0, stream>>>(bq, bk, bv, bo, biasb);
  wt_cvt_k<<<dim3(32,32,4), dim3(32,8), 0, stream>>>(Wq, Wk, Wv, Wo, Wt);

  // 2a) q,k projections via gemm8: grid = 4(N) x 32(M) x 2(z) = 256 = 1 round
  gemm8_k<1><<<256, 512, 0, stream>>>(qkvbf, Wt, QKV, biasb,
      8192, 1024, 1024, 8388608LL, 1048576LL, 8388608LL, 1024LL, 1.0f, 2, 5);

  // 2b) V projection, transposed output: Vt[d, bs] = Wv^T @ v_bf^T + bv[d]
  gemm4_k<1,1><<<256, 512, 0, stream>>>(Wt + 2097152LL, vbf, Vt, biasb + 2048,
      1024, 1024, 1024, 8192, 0LL, 0LL, 0LL, 0LL, 1.0f, 6, 2);

  // 3) scores = Q @ K^T / 32 -> bf16 P (256 blocks = 1 round)
  gemm8_k<1><<<256, 512, 0, stream>>>(Qp, Kp, P, nullptr,
      2048, 2048, 1024, 2097152LL, 2097152LL, 4194304LL, 0LL, 0.03125f, 3, 3);

  // 4) P = softmax_rows(P) in place
  softmax_bf_k<<<dim3(8192), 256, 0, stream>>>(P);

  // 5) xt[d, q] = Vt[d,:] . P[q,:]  (A = Vt + z*2048 cols, lda=8192)
  gemm4_k<1,0><<<256, 512, 0, stream>>>(Vt, P, xt, nullptr,
      2048, 8192, 2048, 2048, 2048LL, 4194304LL, 2097152LL, 0LL, 1.0f, 4, 2);

  // 6) out = reshape(xt) @ Wo + bo; xt reinterpreted [2048][1024] row-major per z
  gemm4_k<0,0><<<256, 512, 0, stream>>>(xt, Wt + 3145728LL, (float*)d_out,
      biasb + 3072, 1024, 1024, 1024, 1024, 2097152LL, 0LL, 2097152LL, 0LL, 1.0f, 3, 3);
}